// Round 11
// baseline (844.138 us; speedup 1.0000x reference)
//
#include <hip/hip_runtime.h>
#include <cstdint>
#include <cstddef>

typedef unsigned int  u32;
typedef unsigned short u16;
typedef _Float16 f16;
typedef _Float16 f16x2 __attribute__((ext_vector_type(2)));
typedef _Float16 half8 __attribute__((ext_vector_type(8)));
typedef float    f32x4v __attribute__((ext_vector_type(4)));
typedef int      i32x4 __attribute__((ext_vector_type(4)));

#define BATCH 64
#define TSEQ  512
#define DEMB  300
#define KPAD  320
#define HDIM  256
#define G4    1024
#define NCLS  9

__device__ __forceinline__ u32 packf16(float a, float b) {
  f16x2 v; v.x = (f16)a; v.y = (f16)b;
  return __builtin_bit_cast(u32, v);
}
__device__ __forceinline__ float f16f(u16 x) {
  return (float)__builtin_bit_cast(f16, x);
}
__device__ __forceinline__ float sigm_fast(float x) {
  return __builtin_amdgcn_rcpf(1.f + __expf(-x));
}
__device__ __forceinline__ float tanh_fast(float x) {
  float ax = __builtin_fabsf(x);
  float e = __expf(-2.f * ax);
  float t = (1.f - e) * __builtin_amdgcn_rcpf(1.f + e);
  return copysignf(t, x);
}

// ---------------- P1: embf16[v][320] = f16(emb[v][0..299]), zero-pad 300..319 ----
__global__ __launch_bounds__(256) void embcvt_k(const float* __restrict__ emb,
                                                u16* __restrict__ out) {
  const int v  = blockIdx.x * 16 + (threadIdx.x >> 4);
  const int kc = threadIdx.x & 15;
  uint2* __restrict__ dst = (uint2*)(out + (size_t)v * KPAD + kc * 20);
  if (kc < 15) {
    const float4* __restrict__ s4 = (const float4*)(emb + (size_t)v * DEMB + kc * 20);
    float4 f0 = s4[0], f1 = s4[1], f2 = s4[2], f3 = s4[3], f4 = s4[4];
    dst[0] = make_uint2(packf16(f0.x, f0.y), packf16(f0.z, f0.w));
    dst[1] = make_uint2(packf16(f1.x, f1.y), packf16(f1.z, f1.w));
    dst[2] = make_uint2(packf16(f2.x, f2.y), packf16(f2.z, f2.w));
    dst[3] = make_uint2(packf16(f3.x, f3.y), packf16(f3.z, f3.w));
    dst[4] = make_uint2(packf16(f4.x, f4.y), packf16(f4.z, f4.w));
  } else {
#pragma unroll
    for (int j = 0; j < 5; ++j) dst[j] = make_uint2(0u, 0u);
  }
}

// ---------------- P2: wkt[dir][col][320] = f16(Wk[k][col]), zero-pad k>=300 -----
__global__ __launch_bounds__(256) void wkt_k(const float* __restrict__ Wk_f,
                                             const float* __restrict__ Wk_b,
                                             u16* __restrict__ wkt) {
  const int dir = blockIdx.y;
  const float* __restrict__ Wk = dir ? Wk_b : Wk_f;
  const int col = blockIdx.x * 16 + (threadIdx.x >> 4);
  const int kc  = threadIdx.x & 15;
  u32* __restrict__ dst = (u32*)(wkt + ((size_t)dir * G4 + col) * KPAD + kc * 20);
  if (kc < 15) {
    float tmp[20];
#pragma unroll
    for (int j = 0; j < 20; ++j) tmp[j] = Wk[(size_t)(kc * 20 + j) * G4 + col];
#pragma unroll
    for (int j = 0; j < 10; ++j) dst[j] = packf16(tmp[2 * j], tmp[2 * j + 1]);
  } else {
#pragma unroll
    for (int j = 0; j < 10; ++j) dst[j] = 0u;
  }
}

// ---------------- P3: wr8[dir][col][256] = int8(Wr[k][col] * 512), k-major ----
__global__ __launch_bounds__(256) void wr8_k(const float* __restrict__ Wr_f,
                                             const float* __restrict__ Wr_b,
                                             signed char* __restrict__ wr8) {
  const int dir = blockIdx.y;
  const float* __restrict__ Wr = dir ? Wr_b : Wr_f;
  const int col = blockIdx.x * 16 + (threadIdx.x >> 4);
  const int k0  = (threadIdx.x & 15) * 16;
  float tmp[16];
#pragma unroll
  for (int j = 0; j < 16; ++j) tmp[j] = Wr[(size_t)(k0 + j) * G4 + col];
  u32 pw[4];
#pragma unroll
  for (int jj = 0; jj < 4; ++jj) {
    u32 p = 0;
#pragma unroll
    for (int b = 0; b < 4; ++b) {
      int q = (int)__builtin_rintf(tmp[4 * jj + b] * 512.f);
      q = q > 127 ? 127 : (q < -127 ? -127 : q);
      p |= ((u32)(q & 255)) << (8 * b);
    }
    pw[jj] = p;
  }
  *(uint4*)(wr8 + ((size_t)dir * G4 + col) * HDIM + k0) =
      make_uint4(pw[0], pw[1], pw[2], pw[3]);
}

// ---------------- K1: xz = emb[inputs] @ Wk + b  (MFMA f16, pipelined) -------
// Output layout GATE-PACKED for lstm: xzp[dir*B*T + row][j(0..255)][g(0..3)].
__global__ __launch_bounds__(256) void xz_gemm_k(
    const int* __restrict__ inputs, const u16* __restrict__ wkt,
    const u16* __restrict__ embf16, const float* __restrict__ b_f,
    const float* __restrict__ b_b, u16* __restrict__ xzp)
{
  __shared__ __align__(16) u16 As[128 * 40];   // [m][k], k-major, pad 32->40
  __shared__ __align__(16) u16 Bs[128 * 40];   // [n][k], k-major
  const int tid  = threadIdx.x;
  const int wv   = tid >> 6, lane = tid & 63;
  const int quad = lane >> 4, fl = lane & 15;
  const int cbi  = blockIdx.x;                 // 0..15
  const int dir  = cbi >> 3;
  const int cb1  = (cbi & 7) * 128;
  const int rb   = blockIdx.y * 128;
  const float* __restrict__ bias = dir ? b_b : b_f;

  const int sm = tid >> 1, sh = (tid & 1) * 16;          // staging row, k-half
  const int vrow = inputs[rb + sm];
  const u16* __restrict__ asrc = wkt + ((size_t)(dir * G4) + cb1 + sm) * KPAD + sh;
  const u16* __restrict__ bsrc = embf16 + (size_t)vrow * KPAD + sh;

  f32x4v acc[2][8];
#pragma unroll
  for (int bt = 0; bt < 2; ++bt)
#pragma unroll
    for (int i = 0; i < 8; ++i) acc[bt][i] = (f32x4v){0.f, 0.f, 0.f, 0.f};

  uint4 a0v = *(const uint4*)(asrc);
  uint4 a1v = *(const uint4*)(asrc + 8);
  uint4 b0v = *(const uint4*)(bsrc);
  uint4 b1v = *(const uint4*)(bsrc + 8);

  for (int kt = 0; kt < 10; ++kt) {
    *(uint4*)&As[sm * 40 + sh]     = a0v;
    *(uint4*)&As[sm * 40 + sh + 8] = a1v;
    *(uint4*)&Bs[sm * 40 + sh]     = b0v;
    *(uint4*)&Bs[sm * 40 + sh + 8] = b1v;
    __syncthreads();
    if (kt < 9) {                              // prefetch next slice under MFMA
      const int k1 = (kt + 1) * 32;
      a0v = *(const uint4*)(asrc + k1);
      a1v = *(const uint4*)(asrc + k1 + 8);
      b0v = *(const uint4*)(bsrc + k1);
      b1v = *(const uint4*)(bsrc + k1 + 8);
    }
    half8 bf[2];
#pragma unroll
    for (int bt = 0; bt < 2; ++bt)
      bf[bt] = *(const half8*)&Bs[(wv * 32 + bt * 16 + fl) * 40 + quad * 8];
#pragma unroll
    for (int i = 0; i < 8; ++i) {
      half8 af = *(const half8*)&As[(i * 16 + fl) * 40 + quad * 8];
      acc[0][i] = __builtin_amdgcn_mfma_f32_16x16x32_f16(af, bf[0], acc[0][i], 0, 0, 0);
      acc[1][i] = __builtin_amdgcn_mfma_f32_16x16x32_f16(af, bf[1], acc[1][i], 0, 0, 0);
    }
    __syncthreads();
  }
#pragma unroll
  for (int bt = 0; bt < 2; ++bt) {
    const int row = rb + wv * 32 + bt * 16 + fl;         // n = emb row
    u16* __restrict__ obase = xzp + ((size_t)(dir * BATCH * TSEQ + row) << 10);
#pragma unroll
    for (int i = 0; i < 8; ++i) {
      const int mb = cb1 + i * 16 + quad * 4;            // 4 consecutive cols, same gate
      const int g = mb >> 8, jb = mb & 255;
      const float4 bb = *(const float4*)&bias[mb];
      f32x4v v = acc[bt][i];
      u16* op = obase + jb * 4 + g;
      op[0]  = (u16)(packf16(v[0] + bb.x, 0.f) & 0xffffu);
      op[4]  = (u16)(packf16(v[1] + bb.y, 0.f) & 0xffffu);
      op[8]  = (u16)(packf16(v[2] + bb.z, 0.f) & 0xffffu);
      op[12] = (u16)(packf16(v[3] + bb.w, 0.f) & 0xffffu);
    }
  }
}

// ---------------- K2: LSTM recurrence — int8 MFMA, 2 waves/SIMD --------------
// 128 blocks x 512 threads (8 waves = 2 waves/SIMD). Weights: 32 frags = 128
// AGPRs/wave pinned "+a" (round 8-9 lesson: without pinning the compiler
// reloads from L2 every step). Round-11 changes: (1) hrow store DEFERRED one
// step so its HBM ack drains under the MFMA window, not at the barrier
// (removes ~300 cyc/step of vmcnt(0) store-drain); (2) xz gate-packed ->
// one ushort4 load/step instead of 4 scalar u16.
#define MFI(a, b, c) __builtin_amdgcn_mfma_i32_16x16x64_i8(a, b, c, 0, 0, 0)
#define LD8(g, ct, kc) (*(const i32x4*)(wr8w + (size_t)((g) * 256 + 32 * w + (ct) * 16 + l15) * HDIM + (kc) * 64 + q16))
#define DECL8(g, ct) \
  i32x4 W##g##ct##_0 = LD8(g, ct, 0), W##g##ct##_1 = LD8(g, ct, 1), \
        W##g##ct##_2 = LD8(g, ct, 2), W##g##ct##_3 = LD8(g, ct, 3); \
  asm volatile("" : "+a"(W##g##ct##_0), "+a"(W##g##ct##_1), \
                    "+a"(W##g##ct##_2), "+a"(W##g##ct##_3));
#define TILE(g, ct) \
  i32x4 ac##g##ct = (i32x4){0, 0, 0, 0}; \
  ac##g##ct = MFI(af0, W##g##ct##_0, ac##g##ct); \
  ac##g##ct = MFI(af1, W##g##ct##_1, ac##g##ct); \
  ac##g##ct = MFI(af2, W##g##ct##_2, ac##g##ct); \
  ac##g##ct = MFI(af3, W##g##ct##_3, ac##g##ct);

__global__ __launch_bounds__(512, 2) void lstm_k(
    const u16* __restrict__ xzp, const signed char* __restrict__ wr8,
    const int* __restrict__ lengths, u16* __restrict__ hcat)
{
  const int chain = blockIdx.x;
  const int dir   = chain >> 6;
  const int batch = chain & 63;
  const int tid  = threadIdx.x;
  const int w    = tid >> 6;
  const int lane = tid & 63;
  const int quad = lane >> 4, l15 = lane & 15;
  const int q16  = quad * 16;
  const int ctsel = quad & 1;
  const int j    = 32 * w + ctsel * 16 + l15;   // this thread's h-index
  const int wr   = quad < 2;                    // writer lane for index j
  const float DEQ = 1.f / (512.f * 127.f);

  __shared__ __align__(16) signed char hpk[2][256];   // double-buffered h (i8)

  const signed char* __restrict__ wr8w = wr8 + (size_t)dir * G4 * HDIM;

  // 8 tiles x 4 k-chunks = 32 frags = 128 AGPRs, pinned
  DECL8(0, 0) DECL8(0, 1) DECL8(1, 0) DECL8(1, 1)
  DECL8(2, 0) DECL8(2, 1) DECL8(3, 0) DECL8(3, 1)

  if (tid < 256) hpk[0][tid] = 0;

  float c = 0.f, h = 0.f;
  const int len = lengths[batch];
  const u16* __restrict__ xzb = xzp + ((size_t)(dir * BATCH + batch) * TSEQ << 10);
  u16* __restrict__ hrow = hcat + (size_t)batch * TSEQ * 512 + dir * 256;
  __syncthreads();

  int tt = dir ? (TSEQ - 1) : 0;
  const int dt = dir ? -1 : 1;
  ushort4 xv = *(const ushort4*)(xzb + ((size_t)tt << 10) + j * 4);
  u16 hbits_prev = 0;
  int  tt_prev = 0;

  for (int st = 0; st < TSEQ; ++st) {
    const int ttn = (st == TSEQ - 1) ? tt : tt + dt;
    ushort4 xn = *(const ushort4*)(xzb + ((size_t)ttn << 10) + j * 4);  // prefetch

    const int par = st & 1;
    const signed char* hb = &hpk[par][0];
    // A-frags: h replicated across rows; lane reads k = kc*64 + quad*16 .. +15
    i32x4 af0 = *(const i32x4*)(hb + q16);
    i32x4 af1 = *(const i32x4*)(hb + 64 + q16);
    i32x4 af2 = *(const i32x4*)(hb + 128 + q16);
    i32x4 af3 = *(const i32x4*)(hb + 192 + q16);

    // previous step's h store: ack drains under this step's MFMA window
    if (st > 0 && wr) hrow[(size_t)tt_prev * 512 + j] = hbits_prev;

    TILE(0, 0) TILE(0, 1)    // gate i, col-subtiles 0,1
    TILE(1, 0) TILE(1, 1)    // gate f
    TILE(2, 0) TILE(2, 1)    // gate g
    TILE(3, 0) TILE(3, 1)    // gate o

    int ri = ctsel ? ac01[0] : ac00[0];
    int rf = ctsel ? ac11[0] : ac10[0];
    int rg = ctsel ? ac21[0] : ac20[0];
    int ro = ctsel ? ac31[0] : ac30[0];

    float zi = (float)ri * DEQ + f16f(xv.x);
    float zf = (float)rf * DEQ + f16f(xv.y);
    float zg = (float)rg * DEQ + f16f(xv.z);
    float zo = (float)ro * DEQ + f16f(xv.w);
    float ig = sigm_fast(zi);
    float fg = sigm_fast(zf);
    float gg = tanh_fast(zg);
    float og = sigm_fast(zo);
    float cn = fg * c + ig * gg;
    float hn = og * tanh_fast(cn);
    if (tt < len) { c = cn; h = hn; }            // masked step: hold state
    u32 hb2 = packf16(h, h);
    if (wr) {
      int hq = (int)__builtin_rintf(h * 127.f);
      hpk[par ^ 1][j] = (signed char)hq;
    }
    hbits_prev = (u16)(hb2 & 0xffffu);
    tt_prev = tt;
    __syncthreads();
    xv = xn; tt = ttn;
  }
  if (wr) hrow[(size_t)tt_prev * 512 + j] = hbits_prev;
}

// ---------------- K3: logits = hcat @ dense_W + dense_b ----------------
__global__ __launch_bounds__(256) void dense_k(
    const u16* __restrict__ hcat, const float* __restrict__ W,
    const float* __restrict__ bias, float* __restrict__ out)
{
  const int lane = threadIdx.x & 63;
  const int wv = threadIdx.x >> 6;
  const int rowbase = (blockIdx.x * 4 + wv) * 8;
  for (int rr = 0; rr < 8; ++rr) {
    const int row = rowbase + rr;
    const u16* __restrict__ hr = hcat + (size_t)row * 512;
    float hv[8];
#pragma unroll
    for (int i = 0; i < 8; ++i)
      hv[i] = f16f(hr[i * 64 + lane]);
    float myout = 0.f;
#pragma unroll
    for (int cc = 0; cc < 9; ++cc) {
      float p = 0.f;
#pragma unroll
      for (int i = 0; i < 8; ++i)
        p = fmaf(hv[i], W[(size_t)(i * 64 + lane) * 9 + cc], p);
#pragma unroll
      for (int o = 32; o > 0; o >>= 1) p += __shfl_xor(p, o);
      if (lane == cc) myout = p + bias[cc];
    }
    if (lane < 9) out[(size_t)row * 9 + lane] = myout;
  }
}

// ---------------- K4: CRF log-likelihood + trans copy ----------------
__global__ __launch_bounds__(64) void crf_k(
    const float* __restrict__ logits, const int* __restrict__ tags,
    const int* __restrict__ lengths, const float* __restrict__ trans,
    float* __restrict__ out_ll, float* __restrict__ out_trans)
{
  const int b = blockIdx.x;
  const int lane = threadIdx.x;
  const int len = lengths[b];
  const float* __restrict__ lg = logits + (size_t)b * TSEQ * NCLS;
  const int* __restrict__ tg = tags + (size_t)b * TSEQ;

  float ua = 0.f, ba = 0.f;
  for (int t = lane; t < TSEQ; t += 64) {
    int tag = tg[t];
    if (t < len) ua += lg[t * 9 + tag];
    if (t < len - 1) ba += trans[tag * 9 + tg[t + 1]];
  }
  float s = ua + ba;
#pragma unroll
  for (int o = 32; o > 0; o >>= 1) s += __shfl_xor(s, o);

  const int j = (lane < 9) ? lane : 0;
  float trc[9], alpha[9];
#pragma unroll
  for (int i = 0; i < 9; ++i) trc[i] = trans[i * 9 + j];
#pragma unroll
  for (int i = 0; i < 9; ++i) alpha[i] = lg[i];
  float curn = lg[9 + j];                    // logits row t=1, prefetched
  for (int t = 1; t < TSEQ; ++t) {
    if (t >= len) break;                     // mask is monotone
    float nxt = (t + 1 < TSEQ) ? lg[(t + 1) * 9 + j] : 0.f;  // prefetch t+1
    float m = -1e30f;
#pragma unroll
    for (int i = 0; i < 9; ++i) m = fmaxf(m, alpha[i] + trc[i]);
    float ss = 0.f;
#pragma unroll
    for (int i = 0; i < 9; ++i) ss += __expf(alpha[i] + trc[i] - m);
    float nj = __logf(ss) + m + curn;
#pragma unroll
    for (int i = 0; i < 9; ++i) alpha[i] = __shfl(nj, i);
    curn = nxt;
  }
  float m2 = -1e30f;
#pragma unroll
  for (int i = 0; i < 9; ++i) m2 = fmaxf(m2, alpha[i]);
  float s2 = 0.f;
#pragma unroll
  for (int i = 0; i < 9; ++i) s2 += __expf(alpha[i] - m2);
  float lse = __logf(s2) + m2;
  if (lane == 0) out_ll[b] = s - lse;
  if (b == 0)
    for (int i = lane; i < 81; i += 64) out_trans[i] = trans[i];
}

// ---------------- launch ----------------
extern "C" void kernel_launch(void* const* d_in, const int* in_sizes, int n_in,
                              void* d_out, int out_size, void* d_ws, size_t ws_size,
                              hipStream_t stream)
{
  const int*   inputs  = (const int*)d_in[0];
  const int*   lengths = (const int*)d_in[1];
  const int*   targets = (const int*)d_in[2];
  const float* emb     = (const float*)d_in[3];
  const float* Wk_f    = (const float*)d_in[4];
  const float* Wr_f    = (const float*)d_in[5];
  const float* b_f     = (const float*)d_in[6];
  const float* Wk_b    = (const float*)d_in[7];
  const float* Wr_b    = (const float*)d_in[8];
  const float* b_b     = (const float*)d_in[9];
  const float* dense_W = (const float*)d_in[10];
  const float* dense_b = (const float*)d_in[11];
  const float* trans   = (const float*)d_in[12];

  char* ws = (char*)d_ws;
  u16*         wkt    = (u16*)ws;                              //  1,310,720 B
  signed char* wr8    = (signed char*)(ws + 1310720ull);       //    524,288 B
  u16*         embf16 = (u16*)(ws + 1835008ull);               // 19,200,000 B
  u16*         xzp    = (u16*)(ws + 1835008ull + 19200000ull); // 134,217,728 B
  u16*         hcat   = (u16*)(ws + 1835008ull + 19200000ull + 134217728ull); // 33,554,432 B

  float* out_logits = (float*)d_out;
  float* out_ll     = out_logits + (size_t)BATCH * TSEQ * NCLS;
  float* out_trans  = out_ll + BATCH;

  hipLaunchKernelGGL(embcvt_k, dim3(1875), dim3(256), 0, stream, emb, embf16);
  hipLaunchKernelGGL(wkt_k, dim3(64, 2), dim3(256), 0, stream, Wk_f, Wk_b, wkt);
  hipLaunchKernelGGL(wr8_k, dim3(64, 2), dim3(256), 0, stream, Wr_f, Wr_b, wr8);
  hipLaunchKernelGGL(xz_gemm_k, dim3(16, 256), dim3(256), 0, stream,
                     inputs, wkt, embf16, b_f, b_b, xzp);
  hipLaunchKernelGGL(lstm_k, dim3(128), dim3(512), 0, stream,
                     xzp, wr8, lengths, hcat);
  hipLaunchKernelGGL(dense_k, dim3(1024), dim3(256), 0, stream,
                     hcat, dense_W, dense_b, out_logits);
  hipLaunchKernelGGL(crf_k, dim3(64), dim3(64), 0, stream,
                     out_logits, targets, lengths, trans, out_ll, out_trans);
}